// Round 16
// baseline (246.644 us; speedup 1.0000x reference)
//
#include <hip/hip_runtime.h>

// Problem constants (B=1)
constexpr int Cc = 32;
constexpr int Dd = 48;
constexpr int Hh = 96;
constexpr int Ww = 192;
constexpr int TW = 16;           // W-kernel tile width
constexpr int NT = Ww / TW;      // 12 tiles
constexpr float NEGBIG = -3.402823466e+38f;

// ws layout (fp16 pairs in u32): ws[((c*48 + wblk)*96 + h)*96 + d*2 + u]
// where wblk = w/4, u = (w%4)/2. 32*48*96*96 u32 = 56.6 MB.
constexpr size_t WSNEED = (size_t)Cc * 48 * Hh * 96 * 4;

// ---- DPP helpers ------------------------------------------------------------
// NOTE: must use __builtin_amdgcn_update_dpp (not inline asm) — the compiler's
// hazard recognizer inserts the required VALU->DPP wait states only for
// compiler-known DPP ops. Inline-asm DPP caused silent corruption (round 3).
template <int CTRL, int RM>
__device__ __forceinline__ float dppmov(float v) {
    int i = __builtin_bit_cast(int, v);
    int r = __builtin_amdgcn_update_dpp(i, i, CTRL, RM, 0xF, false);
    return __builtin_bit_cast(float, r);
}

__device__ __forceinline__ float rdlane(float v, int idx) {
    int r = __builtin_amdgcn_readlane(__builtin_bit_cast(int, v), idx);
    return __builtin_bit_cast(float, r);
}

__device__ __forceinline__ unsigned f2h(float v) {
    return (unsigned)__builtin_bit_cast(unsigned short, (_Float16)v);
}
__device__ __forceinline__ float h2f(unsigned short u) {
    return (float)__builtin_bit_cast(_Float16, u);
}

// Max over lanes 0..47, broadcast. Row-confined: junk in lanes 48..63 never
// enters the reduction.
__device__ __forceinline__ float wave_max48(float v) {
    v = fmaxf(v, dppmov<0x111, 0xF>(v));   // row_shr:1
    v = fmaxf(v, dppmov<0x112, 0xF>(v));   // row_shr:2
    v = fmaxf(v, dppmov<0x114, 0xF>(v));   // row_shr:4
    v = fmaxf(v, dppmov<0x118, 0xF>(v));   // row_shr:8
    v = fmaxf(v, dppmov<0x142, 0x2>(v));   // row_bcast:15 -> row1: lane31=max(0..31)
    v = fmaxf(v, dppmov<0x143, 0x4>(v));   // row_bcast:31 -> row2: lane47=max(0..47)
    return rdlane(v, 47);
}

// One SGA step (lane = d). Lanes >= 48 compute garbage that never propagates
// back into lanes 0..47.
__device__ __forceinline__ float sga_step(float A, float cs, float g0v, float g1v, float g2v,
                                          float g3v, float g4v, bool is47, bool first) {
    float dm1 = dppmov<0x138, 0xF>(A);             // wave_shr:1, lane0 keeps own
    float dp1 = dppmov<0x130, 0xF>(A);             // wave_shl:1
    dp1 = is47 ? A : dp1;                          // d+1 clamp at d=47
    float mx = wave_max48(A);
    float r = g0v * cs + g1v * A + g2v * dm1 + g3v * dp1 + g4v * mx;
    return first ? cs : r;
}

// 16 recurrence steps over one tile (W kernel). DESC = direction in tile.
// STASH = pack results fp16 into tr; else combine with opposite stash rr and
// write results to xo.
template <bool DESC, bool STASH>
__device__ __forceinline__ void w6_run16(float& A, unsigned* tr, const unsigned* rr,
                                         float (*xo)[TW + 1], float gA, float g4r,
                                         int lane, int dl, bool is47, bool firstTile) {
#pragma unroll
    for (int k = 0; k < TW; ++k) {
        const int wk = DESC ? (TW - 1 - k) : k;
        const float g0v = rdlane(gA, wk);
        const float g1v = rdlane(gA, 16 + wk);
        const float g2v = rdlane(gA, 32 + wk);
        const float g3v = rdlane(gA, 48 + wk);
        const float g4v = rdlane(g4r, wk);
        const float cs = xo[dl][wk];
        A = sga_step(A, cs, g0v, g1v, g2v, g3v, g4v, is47, firstTile && (k == 0));
        if (STASH) {
            const unsigned hu = f2h(A);
            if (!DESC) {
                if ((wk & 1) == 0) tr[wk >> 1] = hu;
                else tr[wk >> 1] |= hu << 16;
            } else {
                if (wk & 1) tr[wk >> 1] = hu << 16;
                else tr[wk >> 1] |= hu;
            }
        } else {
            const unsigned u = rr[wk >> 1];
            const float aop = h2f((unsigned short)((wk & 1) ? (u >> 16) : (u & 0xffffu)));
            if (lane < Dd) xo[lane][wk] = fmaxf(A, aop);
        }
    }
}

// ============================================================================
// W-pair kernel sga_w6 (round-14/15): meet-in-the-middle, 2 waves/block,
// wave0=fwd(ga), wave1=rev(gb) simultaneous; fp16 LDS stash; one barrier.
// WS=true: at flush, max in the H result read from ws (blocked fp16 layout),
// writing out = max(a0,a1,a2,a3) once.
// ============================================================================
template <bool WS>
__global__ __launch_bounds__(128, 4) void sga_w6(const float* __restrict__ x,
                                                 const float* __restrict__ ga,
                                                 const float* __restrict__ gb,
                                                 float* __restrict__ out,
                                                 const unsigned* __restrict__ ws) {
    __shared__ unsigned sstash[2][48][Dd];   // [dir][lt*8+r][lane] = 18432 B
    __shared__ float xo[2][Dd][TW + 1];      // per-dir x tile / flush tile = 6528 B

    const int bid = blockIdx.x;
    const int c = bid / Hh;
    const int h = bid - c * Hh;
    const int tid = threadIdx.x;
    const int lane = tid & 63;
    const int dir = tid >> 6;            // 0 = fwd (w asc, ga), 1 = rev (w desc, gb)
    const size_t HW = (size_t)Hh * Ww;

    const float* xrow = x + (size_t)c * Dd * HW + (size_t)h * Ww;
    const float* grow = (dir ? gb : ga) + (size_t)c * 5 * HW + (size_t)h * Ww;
    float* orow = out + (size_t)c * Dd * HW + (size_t)h * Ww;

    const int dl = (lane < Dd) ? lane : (Dd - 1);
    const bool is47 = (lane == Dd - 1);

    int srow[3], scol[3];
#pragma unroll
    for (int i = 0; i < 3; ++i) {
        const int e4 = lane + i * 64;
        srow[i] = e4 >> 2;
        scol[i] = (e4 & 3) * 4;
    }
    const int gk = lane >> 4;
    const int gwi = lane & 15;

    float4 pre[3];
    float gA, g4r, gAn = 0.f, g4n = 0.f;
    unsigned tr[8];

    // prologue: first tile of own direction -> own xo half
    {
        const int t = dir ? (NT - 1) : 0;
        const int w0 = t * TW;
#pragma unroll
        for (int i = 0; i < 3; ++i)
            pre[i] = *reinterpret_cast<const float4*>(xrow + (size_t)srow[i] * HW + w0 + scol[i]);
        gA = grow[(size_t)gk * HW + w0 + gwi];
        g4r = grow[(size_t)4 * HW + w0 + gwi];
#pragma unroll
        for (int i = 0; i < 3; ++i) {
            xo[dir][srow[i]][scol[i] + 0] = pre[i].x;
            xo[dir][srow[i]][scol[i] + 1] = pre[i].y;
            xo[dir][srow[i]][scol[i] + 2] = pre[i].z;
            xo[dir][srow[i]][scol[i] + 3] = pre[i].w;
        }
    }

    float A = NEGBIG;

    for (int tt = 0; tt < NT; ++tt) {
        if (tt == NT / 2) __syncthreads();   // opposite stash complete

        const int t = dir ? (NT - 1 - tt) : tt;
        const int w0 = t * TW;

        // prefetch next tile of own direction (hidden under the 16-step chain)
        if (tt + 1 < NT) {
            const int wn = (dir ? (NT - 2 - tt) : (tt + 1)) * TW;
#pragma unroll
            for (int i = 0; i < 3; ++i)
                pre[i] = *reinterpret_cast<const float4*>(xrow + (size_t)srow[i] * HW + wn + scol[i]);
            gAn = grow[(size_t)gk * HW + wn + gwi];
            g4n = grow[(size_t)4 * HW + wn + gwi];
        }

        unsigned rr[8];
        unsigned wsv[6];
        if (tt >= NT / 2) {
            // opposite wave stashed tile t at local index NT-1-tt
#pragma unroll
            for (int r = 0; r < 8; ++r) rr[r] = sstash[dir ^ 1][(NT - 1 - tt) * 8 + r][dl];
            if constexpr (WS) {
                // H result for this tile (issued early; consumed after run16)
#pragma unroll
                for (int i = 0; i < 3; ++i) {
                    const int wb = (w0 + scol[i]) >> 2;   // 4-wide ws blocks
                    const size_t base =
                        (((size_t)c * 48 + wb) * Hh + h) * 96 + srow[i] * 2;
                    wsv[2 * i] = ws[base];          // w0+scol+0,1
                    wsv[2 * i + 1] = ws[base + 1];  // w0+scol+2,3
                }
            }
        }

        if (tt < NT / 2) {
            if (dir == 0)
                w6_run16<false, true>(A, tr, rr, xo[0], gA, g4r, lane, dl, is47, tt == 0);
            else
                w6_run16<true, true>(A, tr, rr, xo[1], gA, g4r, lane, dl, is47, tt == 0);
            if (lane < Dd) {
#pragma unroll
                for (int r = 0; r < 8; ++r) sstash[dir][tt * 8 + r][lane] = tr[r];
            }
        } else {
            if (dir == 0)
                w6_run16<false, false>(A, tr, rr, xo[0], gA, g4r, lane, dl, is47, false);
            else
                w6_run16<true, false>(A, tr, rr, xo[1], gA, g4r, lane, dl, is47, false);
            // flush combined tile (coalesced float4, full 64B lines)
#pragma unroll
            for (int i = 0; i < 3; ++i) {
                float4 v;
                v.x = xo[dir][srow[i]][scol[i] + 0];
                v.y = xo[dir][srow[i]][scol[i] + 1];
                v.z = xo[dir][srow[i]][scol[i] + 2];
                v.w = xo[dir][srow[i]][scol[i] + 3];
                if constexpr (WS) {
                    v.x = fmaxf(v.x, h2f((unsigned short)(wsv[2 * i] & 0xffffu)));
                    v.y = fmaxf(v.y, h2f((unsigned short)(wsv[2 * i] >> 16)));
                    v.z = fmaxf(v.z, h2f((unsigned short)(wsv[2 * i + 1] & 0xffffu)));
                    v.w = fmaxf(v.w, h2f((unsigned short)(wsv[2 * i + 1] >> 16)));
                }
                *reinterpret_cast<float4*>(orow + (size_t)srow[i] * HW + w0 + scol[i]) = v;
            }
        }

        if (tt + 1 < NT) {
#pragma unroll
            for (int i = 0; i < 3; ++i) {
                xo[dir][srow[i]][scol[i] + 0] = pre[i].x;
                xo[dir][srow[i]][scol[i] + 1] = pre[i].y;
                xo[dir][srow[i]][scol[i] + 2] = pre[i].z;
                xo[dir][srow[i]][scol[i] + 3] = pre[i].w;
            }
            gA = gAn;
            g4r = g4n;
        }
    }
}

// ============================================================================
// H-pair kernel sga_h10 = round-5 h3 geometry (4 cols x 2 dirs = 8 waves,
// 512 thr, KH2=4, quad XCD swizzle, 70 KB LDS -> 2 blocks/CU so co-resident
// blocks hide each other's barrier drains) with blocked fp16 ws output
// (WS=true: no out access; 384B-contiguous packed stores). WS=false: h3's
// fp32 out RMW fallback.
// ============================================================================
constexpr int WT2 = 4;
constexpr int KH2 = 4;
constexpr int NP2 = Hh / KH2;     // 24 periods
constexpr int HALF = NP2 / 2;     // 12

template <bool WS>
__global__ __launch_bounds__(512, 4) void sga_h10(const float* __restrict__ x,
                                                  const float* __restrict__ gf,
                                                  const float* __restrict__ gr,
                                                  float* __restrict__ out,
                                                  unsigned* __restrict__ ws) {
    __shared__ _Float16 stash[WT2][2][Hh / 2][Dd];   // 36864 B
    __shared__ float xs[2][2][KH2][Dd][WT2 + 1];     // 15360 B (pad 5: gcd(5,32)=1)
    __shared__ float osb[2][2][KH2][Dd][WT2 + 1];    // 15360 B
    __shared__ float gs[2][2][KH2][WT2][8];          // 4096 B (8-pad: aligned float4)
    // total 71680 B -> 2 blocks/CU

    // quad XCD swizzle: the 4 blocks covering one 64B line-span (16 consecutive
    // w) are consecutive in L -> same XCD -> line fetched once.
    const int xcd = blockIdx.x & 7;
    const int within = blockIdx.x >> 3;          // 0..191
    const int L = xcd * 192 + within;
    const int quad = L >> 2, sub = L & 3;
    const int c = quad / 12;
    const int wq = quad % 12;
    const int w0 = wq * 16 + sub * 4;

    const int tid = threadIdx.x;
    const int lane = tid & 63;
    const int wv = tid >> 6;            // 0..7
    const int col = wv >> 1;            // 0..3
    const int dir = wv & 1;             // 0=fwd(h asc), 1=rev(h desc)
    const size_t HW = (size_t)Hh * Ww;

    const float* xb = x + (size_t)c * Dd * HW;
    const float* gfb = gf + (size_t)c * 5 * HW;
    const float* grb = gr + (size_t)c * 5 * HW;
    float* ob = out + (size_t)c * Dd * HW;

    const int dl = (lane < Dd) ? lane : (Dd - 1);
    const bool is47 = (lane == Dd - 1);

    // x / out staging decomposition: idx = tid + j*512 over [2cu][4hp][48d][4w]
    int w_[3], d_[3], hp_[3], cu_[3];
    size_t xoff_[3];
#pragma unroll
    for (int j = 0; j < 3; ++j) {
        const int idx = tid + j * 512;
        w_[j] = idx & 3;
        const int t = idx >> 2;
        d_[j] = t % Dd;
        const int t2 = t / Dd;
        hp_[j] = t2 & 3;
        cu_[j] = t2 >> 2;
        xoff_[j] = (size_t)d_[j] * HW + (w0 + w_[j]);
    }
    // g staging (tid < 160): [2cu][4hp][5k][4w], w fastest
    const int gw_ = tid & 3;
    const int gk_ = (tid >> 2) % 5;
    const int ghc = (tid >> 2) / 5;       // 0..7
    const int ghp_ = ghc & 3;
    const int gcu_ = ghc >> 2;
    const bool gst = tid < 160;
    // WS flush mapping: idx = tid + j*512 over [2cu][4hp][48d][2u] = 768
    int fu_[2], fd_[2], fhp_[2], fcu_[2];
    bool fval_[2];
#pragma unroll
    for (int j = 0; j < 2; ++j) {
        int idx = tid + j * 512;
        fval_[j] = idx < 768;
        if (idx >= 768) idx = 767;
        fu_[j] = idx & 1;
        const int t = idx >> 1;
        fd_[j] = t % Dd;
        const int r = t / Dd;
        fhp_[j] = r & 3;
        fcu_[j] = r >> 2;
    }
    const size_t wsblk = ((size_t)c * 48 + (w0 >> 2)) * Hh;   // + h, then *96

    auto hofs = [&](int cur, int P, int hp) -> int {
        const int p = P * KH2 + hp;
        return cur ? (Hh - 1 - p) : p;
    };

    float xr_[3], grg = 0.f, orr[2][3];

    // prologue: stage period 0 into buf 0
    {
#pragma unroll
        for (int j = 0; j < 3; ++j) xr_[j] = xb[xoff_[j] + (size_t)hofs(cu_[j], 0, hp_[j]) * Ww];
        if (gst) {
            const float* gp = gcu_ ? grb : gfb;
            grg = gp[(size_t)gk_ * HW + (size_t)hofs(gcu_, 0, ghp_) * Ww + (w0 + gw_)];
        }
#pragma unroll
        for (int j = 0; j < 3; ++j) xs[0][cu_[j]][hp_[j]][d_[j]][w_[j]] = xr_[j];
        if (gst) gs[0][gcu_][ghp_][gw_][gk_] = grg;
    }
    __syncthreads();

    float A = NEGBIG;

#pragma unroll 2
    for (int p = 0; p < NP2; ++p) {
        const int pb = p & 1;

        // (1) issue staging loads for period p+1
        if (p + 1 < NP2) {
#pragma unroll
            for (int j = 0; j < 3; ++j)
                xr_[j] = xb[xoff_[j] + (size_t)hofs(cu_[j], p + 1, hp_[j]) * Ww];
            if (gst) {
                const float* gp = gcu_ ? grb : gfb;
                grg = gp[(size_t)gk_ * HW + (size_t)hofs(gcu_, p + 1, ghp_) * Ww + (w0 + gw_)];
            }
        }
        // (2) fallback only: out-reads for THIS period (flushed next period)
        if constexpr (!WS) {
            if (p >= HALF) {
#pragma unroll
                for (int j = 0; j < 3; ++j)
                    orr[pb][j] = ob[xoff_[j] + (size_t)hofs(cu_[j], p, hp_[j]) * Ww];
            }
        }

        // (3) compute KH2 windows
#pragma unroll
        for (int hp = 0; hp < KH2; ++hp) {
            const int q = p * KH2 + hp;
            const float cs = xs[pb][dir][hp][dl][col];
            const float* gbase = &gs[pb][dir][hp][col][0];
            const float4 g03 = *reinterpret_cast<const float4*>(gbase);
            const float g4 = gbase[4];
            A = sga_step(A, cs, g03.x, g03.y, g03.z, g03.w, g4, is47, q == 0);
            if (q < Hh / 2) {
                if (lane < Dd) stash[col][dir][q][lane] = (_Float16)A;
            } else {
                const float s = (float)stash[col][dir ^ 1][Hh - 1 - q][dl];
                const float o = fmaxf(A, s);
                if (lane < Dd) osb[pb][dir][hp][lane][col] = o;
            }
        }

        // (4) flush period p-1 osb
        if (p > HALF) {
            if constexpr (WS) {
#pragma unroll
                for (int j = 0; j < 2; ++j) {
                    if (fval_[j]) {
                        const float* orow = &osb[pb ^ 1][fcu_[j]][fhp_[j]][fd_[j]][0];
                        const unsigned pk =
                            f2h(orow[2 * fu_[j]]) | (f2h(orow[2 * fu_[j] + 1]) << 16);
                        const int hh = hofs(fcu_[j], p - 1, fhp_[j]);
                        ws[(wsblk + hh) * 96 + fd_[j] * 2 + fu_[j]] = pk;
                    }
                }
            } else {
#pragma unroll
                for (int j = 0; j < 3; ++j) {
                    const float v = fmaxf(osb[pb ^ 1][cu_[j]][hp_[j]][d_[j]][w_[j]],
                                          orr[pb ^ 1][j]);
                    ob[xoff_[j] + (size_t)hofs(cu_[j], p - 1, hp_[j]) * Ww] = v;
                }
            }
        }

        // (5) commit staged regs for p+1
        if (p + 1 < NP2) {
#pragma unroll
            for (int j = 0; j < 3; ++j) xs[pb ^ 1][cu_[j]][hp_[j]][d_[j]][w_[j]] = xr_[j];
            if (gst) gs[pb ^ 1][gcu_][ghp_][gw_][gk_] = grg;
        }
        __syncthreads();
    }

    // epilogue: flush last period (p = NP2-1, pb = 1)
    if constexpr (WS) {
#pragma unroll
        for (int j = 0; j < 2; ++j) {
            if (fval_[j]) {
                const float* orow = &osb[1][fcu_[j]][fhp_[j]][fd_[j]][0];
                const unsigned pk = f2h(orow[2 * fu_[j]]) | (f2h(orow[2 * fu_[j] + 1]) << 16);
                const int hh = hofs(fcu_[j], NP2 - 1, fhp_[j]);
                ws[(wsblk + hh) * 96 + fd_[j] * 2 + fu_[j]] = pk;
            }
        }
    } else {
#pragma unroll
        for (int j = 0; j < 3; ++j) {
            const float v = fmaxf(osb[1][cu_[j]][hp_[j]][d_[j]][w_[j]], orr[1][j]);
            ob[xoff_[j] + (size_t)hofs(cu_[j], NP2 - 1, hp_[j]) * Ww] = v;
        }
    }
}

extern "C" void kernel_launch(void* const* d_in, const int* in_sizes, int n_in,
                              void* d_out, int out_size, void* d_ws, size_t ws_size,
                              hipStream_t stream) {
    const float* x  = (const float*)d_in[0];
    const float* g0 = (const float*)d_in[1];
    const float* g1 = (const float*)d_in[2];
    const float* g2 = (const float*)d_in[3];
    const float* g3 = (const float*)d_in[4];
    float* out = (float*)d_out;

    if (ws_size >= WSNEED) {
        // H pair -> ws (fp16 blocked, no out access); W pair -> out = max(all 4)
        sga_h10<true><<<Cc * (Ww / WT2), 512, 0, stream>>>(x, g2, g3, out, (unsigned*)d_ws);
        sga_w6<true><<<Cc * Hh, 128, 0, stream>>>(x, g0, g1, out, (const unsigned*)d_ws);
    } else {
        // fallback: W writes out = max(a0,a1); H RMWs out with max(a2,a3) fp32.
        sga_w6<false><<<Cc * Hh, 128, 0, stream>>>(x, g0, g1, out, nullptr);
        sga_h10<false><<<Cc * (Ww / WT2), 512, 0, stream>>>(x, g2, g3, out, nullptr);
    }
}

// Round 17
// 237.855 us; speedup vs baseline: 1.0370x; 1.0370x over previous
//
#include <hip/hip_runtime.h>

// Problem constants (B=1)
constexpr int Cc = 32;
constexpr int Dd = 48;
constexpr int Hh = 96;
constexpr int Ww = 192;
constexpr int TW = 16;           // W-kernel tile width
constexpr int NT = Ww / TW;      // 12 tiles
constexpr float NEGBIG = -3.402823466e+38f;

// ws layout (fp16 pairs in u32): ws[((c*24 + wblk)*96 + h)*192 + d*4 + u]
// where wblk = w/8, u = (w%8)/2. 32*24*96*192 u32 = 56.6 MB.
constexpr size_t WSNEED = (size_t)Cc * 24 * Hh * 192 * 4;

// ---- DPP helpers ------------------------------------------------------------
// NOTE: must use __builtin_amdgcn_update_dpp (not inline asm) — the compiler's
// hazard recognizer inserts the required VALU->DPP wait states only for
// compiler-known DPP ops. Inline-asm DPP caused silent corruption (round 3).
template <int CTRL, int RM>
__device__ __forceinline__ float dppmov(float v) {
    int i = __builtin_bit_cast(int, v);
    int r = __builtin_amdgcn_update_dpp(i, i, CTRL, RM, 0xF, false);
    return __builtin_bit_cast(float, r);
}

__device__ __forceinline__ float rdlane(float v, int idx) {
    int r = __builtin_amdgcn_readlane(__builtin_bit_cast(int, v), idx);
    return __builtin_bit_cast(float, r);
}

__device__ __forceinline__ unsigned f2h(float v) {
    return (unsigned)__builtin_bit_cast(unsigned short, (_Float16)v);
}
__device__ __forceinline__ float h2f(unsigned short u) {
    return (float)__builtin_bit_cast(_Float16, u);
}

// Max over lanes 0..47, broadcast. Row-confined: junk in lanes 48..63 never
// enters the reduction.
__device__ __forceinline__ float wave_max48(float v) {
    v = fmaxf(v, dppmov<0x111, 0xF>(v));   // row_shr:1
    v = fmaxf(v, dppmov<0x112, 0xF>(v));   // row_shr:2
    v = fmaxf(v, dppmov<0x114, 0xF>(v));   // row_shr:4
    v = fmaxf(v, dppmov<0x118, 0xF>(v));   // row_shr:8
    v = fmaxf(v, dppmov<0x142, 0x2>(v));   // row_bcast:15 -> row1: lane31=max(0..31)
    v = fmaxf(v, dppmov<0x143, 0x4>(v));   // row_bcast:31 -> row2: lane47=max(0..47)
    return rdlane(v, 47);
}

// One SGA step (lane = d). Lanes >= 48 compute garbage that never propagates
// back into lanes 0..47.
__device__ __forceinline__ float sga_step(float A, float cs, float g0v, float g1v, float g2v,
                                          float g3v, float g4v, bool is47, bool first) {
    float dm1 = dppmov<0x138, 0xF>(A);             // wave_shr:1, lane0 keeps own
    float dp1 = dppmov<0x130, 0xF>(A);             // wave_shl:1
    dp1 = is47 ? A : dp1;                          // d+1 clamp at d=47
    float mx = wave_max48(A);
    float r = g0v * cs + g1v * A + g2v * dm1 + g3v * dp1 + g4v * mx;
    return first ? cs : r;
}

// 16 recurrence steps over one tile (W kernel). DESC = direction in tile.
// STASH = pack results fp16 into tr; else combine with opposite stash rr and
// write results to xo.
template <bool DESC, bool STASH>
__device__ __forceinline__ void w6_run16(float& A, unsigned* tr, const unsigned* rr,
                                         float (*xo)[TW + 1], float gA, float g4r,
                                         int lane, int dl, bool is47, bool firstTile) {
#pragma unroll
    for (int k = 0; k < TW; ++k) {
        const int wk = DESC ? (TW - 1 - k) : k;
        const float g0v = rdlane(gA, wk);
        const float g1v = rdlane(gA, 16 + wk);
        const float g2v = rdlane(gA, 32 + wk);
        const float g3v = rdlane(gA, 48 + wk);
        const float g4v = rdlane(g4r, wk);
        const float cs = xo[dl][wk];
        A = sga_step(A, cs, g0v, g1v, g2v, g3v, g4v, is47, firstTile && (k == 0));
        if (STASH) {
            const unsigned hu = f2h(A);
            if (!DESC) {
                if ((wk & 1) == 0) tr[wk >> 1] = hu;
                else tr[wk >> 1] |= hu << 16;
            } else {
                if (wk & 1) tr[wk >> 1] = hu << 16;
                else tr[wk >> 1] |= hu;
            }
        } else {
            const unsigned u = rr[wk >> 1];
            const float aop = h2f((unsigned short)((wk & 1) ? (u >> 16) : (u & 0xffffu)));
            if (lane < Dd) xo[lane][wk] = fmaxf(A, aop);
        }
    }
}

// ============================================================================
// W-pair kernel sga_w6 (round-14/15, UNCHANGED): meet-in-the-middle, 2 waves,
// wave0=fwd(ga), wave1=rev(gb) simultaneous; fp16 LDS stash; one barrier.
// WS=true: at flush, max in the H result read from ws, single out write.
// ============================================================================
template <bool WS>
__global__ __launch_bounds__(128, 4) void sga_w6(const float* __restrict__ x,
                                                 const float* __restrict__ ga,
                                                 const float* __restrict__ gb,
                                                 float* __restrict__ out,
                                                 const unsigned* __restrict__ ws) {
    __shared__ unsigned sstash[2][48][Dd];   // [dir][lt*8+r][lane] = 18432 B
    __shared__ float xo[2][Dd][TW + 1];      // per-dir x tile / flush tile = 6528 B

    const int bid = blockIdx.x;
    const int c = bid / Hh;
    const int h = bid - c * Hh;
    const int tid = threadIdx.x;
    const int lane = tid & 63;
    const int dir = tid >> 6;            // 0 = fwd (w asc, ga), 1 = rev (w desc, gb)
    const size_t HW = (size_t)Hh * Ww;

    const float* xrow = x + (size_t)c * Dd * HW + (size_t)h * Ww;
    const float* grow = (dir ? gb : ga) + (size_t)c * 5 * HW + (size_t)h * Ww;
    float* orow = out + (size_t)c * Dd * HW + (size_t)h * Ww;

    const int dl = (lane < Dd) ? lane : (Dd - 1);
    const bool is47 = (lane == Dd - 1);

    int srow[3], scol[3];
#pragma unroll
    for (int i = 0; i < 3; ++i) {
        const int e4 = lane + i * 64;
        srow[i] = e4 >> 2;
        scol[i] = (e4 & 3) * 4;
    }
    const int gk = lane >> 4;
    const int gwi = lane & 15;

    float4 pre[3];
    float gA, g4r, gAn = 0.f, g4n = 0.f;
    unsigned tr[8];

    // prologue: first tile of own direction -> own xo half
    {
        const int t = dir ? (NT - 1) : 0;
        const int w0 = t * TW;
#pragma unroll
        for (int i = 0; i < 3; ++i)
            pre[i] = *reinterpret_cast<const float4*>(xrow + (size_t)srow[i] * HW + w0 + scol[i]);
        gA = grow[(size_t)gk * HW + w0 + gwi];
        g4r = grow[(size_t)4 * HW + w0 + gwi];
#pragma unroll
        for (int i = 0; i < 3; ++i) {
            xo[dir][srow[i]][scol[i] + 0] = pre[i].x;
            xo[dir][srow[i]][scol[i] + 1] = pre[i].y;
            xo[dir][srow[i]][scol[i] + 2] = pre[i].z;
            xo[dir][srow[i]][scol[i] + 3] = pre[i].w;
        }
    }

    float A = NEGBIG;

    for (int tt = 0; tt < NT; ++tt) {
        if (tt == NT / 2) __syncthreads();   // opposite stash complete

        const int t = dir ? (NT - 1 - tt) : tt;
        const int w0 = t * TW;

        // prefetch next tile of own direction (hidden under the 16-step chain)
        if (tt + 1 < NT) {
            const int wn = (dir ? (NT - 2 - tt) : (tt + 1)) * TW;
#pragma unroll
            for (int i = 0; i < 3; ++i)
                pre[i] = *reinterpret_cast<const float4*>(xrow + (size_t)srow[i] * HW + wn + scol[i]);
            gAn = grow[(size_t)gk * HW + wn + gwi];
            g4n = grow[(size_t)4 * HW + wn + gwi];
        }

        unsigned rr[8];
        unsigned wsv[6];
        if (tt >= NT / 2) {
            // opposite wave stashed tile t at local index NT-1-tt
#pragma unroll
            for (int r = 0; r < 8; ++r) rr[r] = sstash[dir ^ 1][(NT - 1 - tt) * 8 + r][dl];
            if constexpr (WS) {
                // H result for this tile (issued early; consumed after run16)
#pragma unroll
                for (int i = 0; i < 3; ++i) {
                    const int wb = (w0 + scol[i]) >> 3;
                    const int wi = scol[i] & 7;    // 0 or 4
                    const size_t base =
                        (((size_t)c * 24 + wb) * Hh + h) * 192 + srow[i] * 4 + (wi >> 1);
                    wsv[2 * i] = ws[base];
                    wsv[2 * i + 1] = ws[base + 1];
                }
            }
        }

        if (tt < NT / 2) {
            if (dir == 0)
                w6_run16<false, true>(A, tr, rr, xo[0], gA, g4r, lane, dl, is47, tt == 0);
            else
                w6_run16<true, true>(A, tr, rr, xo[1], gA, g4r, lane, dl, is47, tt == 0);
            if (lane < Dd) {
#pragma unroll
                for (int r = 0; r < 8; ++r) sstash[dir][tt * 8 + r][lane] = tr[r];
            }
        } else {
            if (dir == 0)
                w6_run16<false, false>(A, tr, rr, xo[0], gA, g4r, lane, dl, is47, false);
            else
                w6_run16<true, false>(A, tr, rr, xo[1], gA, g4r, lane, dl, is47, false);
            // flush combined tile (coalesced float4, full 64B lines)
#pragma unroll
            for (int i = 0; i < 3; ++i) {
                float4 v;
                v.x = xo[dir][srow[i]][scol[i] + 0];
                v.y = xo[dir][srow[i]][scol[i] + 1];
                v.z = xo[dir][srow[i]][scol[i] + 2];
                v.w = xo[dir][srow[i]][scol[i] + 3];
                if constexpr (WS) {
                    v.x = fmaxf(v.x, h2f((unsigned short)(wsv[2 * i] & 0xffffu)));
                    v.y = fmaxf(v.y, h2f((unsigned short)(wsv[2 * i] >> 16)));
                    v.z = fmaxf(v.z, h2f((unsigned short)(wsv[2 * i + 1] & 0xffffu)));
                    v.w = fmaxf(v.w, h2f((unsigned short)(wsv[2 * i + 1] >> 16)));
                }
                *reinterpret_cast<float4*>(orow + (size_t)srow[i] * HW + w0 + scol[i]) = v;
            }
        }

        if (tt + 1 < NT) {
#pragma unroll
            for (int i = 0; i < 3; ++i) {
                xo[dir][srow[i]][scol[i] + 0] = pre[i].x;
                xo[dir][srow[i]][scol[i] + 1] = pre[i].y;
                xo[dir][srow[i]][scol[i] + 2] = pre[i].z;
                xo[dir][srow[i]][scol[i] + 3] = pre[i].w;
            }
            gA = gAn;
            g4r = g4n;
        }
    }
}

// ============================================================================
// H-pair kernel sga_h9 (round-15 structure: 16 waves, KH=4, fp16 stash,
// lockstep dirs, blocked fp16 ws output) + ROUND-17: strength-reduced
// addressing — all per-period offsets advance by constant per-thread strides
// (xoi += xstep etc.) instead of recomputing hofs() muls/selects each period.
// ============================================================================
constexpr int HWT = 8;
constexpr int HKH = 4;
constexpr int HNP = Hh / HKH;     // 24 periods
constexpr int HHALF = HNP / 2;    // 12

template <bool WS>
__global__ __launch_bounds__(1024) void sga_h9(const float* __restrict__ x,
                                               const float* __restrict__ gf,
                                               const float* __restrict__ gr,
                                               float* __restrict__ out,
                                               unsigned* __restrict__ ws) {
    __shared__ _Float16 stash[HWT][2][Hh / 2][Dd];   // 73728 B
    __shared__ float xs[2][2][HKH][Dd][9];           // 27648 B  (pad 9: conflict-free)
    __shared__ float osb[2][2][HKH][Dd][9];          // 27648 B
    __shared__ float gs[2][2][HKH][HWT][8];          // 8192 B   (8-pad: aligned float4)

    // XCD pair-swizzle: blocks covering the two 32B halves of each 64B line
    // (adjacent wt pairs) are 8 apart in blockIdx -> same XCD. Grid = 768.
    const int xcd = blockIdx.x & 7;
    const int within = blockIdx.x >> 3;          // 0..95
    const int pairid = xcd * 48 + (within >> 1); // 0..383
    const int sub = within & 1;
    const int c = pairid / 12;
    const int w0 = ((pairid % 12) * 2 + sub) * HWT;

    const int tid = threadIdx.x;
    const int lane = tid & 63;
    const int wv = tid >> 6;            // 0..15
    const int col = wv >> 1;            // 0..7
    const int dir = wv & 1;             // 0=fwd(h asc), 1=rev(h desc)
    const size_t HW = (size_t)Hh * Ww;

    const float* xb = x + (size_t)c * Dd * HW;
    const float* gfb = gf + (size_t)c * 5 * HW;
    const float* grb = gr + (size_t)c * 5 * HW;
    float* ob = out + (size_t)c * Dd * HW;

    const int dl = (lane < Dd) ? lane : (Dd - 1);
    const bool is47 = (lane == Dd - 1);

    // x staging decomposition: idx = tid + j*1024 over [2][HKH][Dd][HWT]
    int w_[3], d_[3], hp_[3], cu_[3];
    size_t xoff_[3];
    int xoi_[3], xstep_[3];       // incremental h-offset (elements) + stride
#pragma unroll
    for (int j = 0; j < 3; ++j) {
        const int idx = tid + j * 1024;
        w_[j] = idx & 7;
        const int t = idx >> 3;
        d_[j] = t % Dd;
        const int t2 = t / Dd;
        hp_[j] = t2 & 3;
        cu_[j] = t2 >> 2;
        xoff_[j] = (size_t)d_[j] * HW + (w0 + w_[j]);
        const int h0 = cu_[j] ? (Hh - 1 - hp_[j]) : hp_[j];   // hofs(cu,0,hp)
        xoi_[j] = h0 * Ww;
        xstep_[j] = (cu_[j] ? -HKH : HKH) * Ww;
    }
    // g staging (tid < 320): idx over [2][HKH][5][HWT], w fastest (coalesced)
    const int gw_ = tid & 7;
    const int gk_ = (tid >> 3) % 5;
    const int ghc = (tid >> 3) / 5;       // 0..7
    const int ghp_ = ghc & 3;
    const int gcu_ = ghc >> 2;
    const bool gst = tid < 320;
    const float* gp0 = (gcu_ ? grb : gfb) + (size_t)gk_ * HW + (w0 + gw_);
    int goi = (gcu_ ? (Hh - 1 - ghp_) : ghp_) * Ww;
    const int gstep = (gcu_ ? -HKH : HKH) * Ww;
    // WS flush mapping: idx = tid + j*1024 over [2cu][4hp][48d][4u32] = 1536
    int fu_[2], fd_[2], fhp_[2], fcu_[2];
    bool fval_[2];
    size_t fbase_[2];
    int foi_[2], fstep_[2];
    const size_t wsblk192 = (((size_t)c * 24 + (w0 >> 3)) * Hh) * 0 +
                            (((size_t)c * 24 + (w0 >> 3)) * Hh) * 192 / 192 * 192; // see below
#pragma unroll
    for (int j = 0; j < 2; ++j) {
        int idx = tid + j * 1024;
        fval_[j] = idx < 1536;
        if (idx >= 1536) idx = 1535;
        fu_[j] = idx & 3;
        const int t = idx >> 2;
        fd_[j] = t % Dd;
        const int r = t / Dd;
        fhp_[j] = r & 3;
        fcu_[j] = r >> 2;
        fbase_[j] = (((size_t)c * 24 + (w0 >> 3)) * Hh) * 192 + fd_[j] * 4 + fu_[j];
        const int hh0 = fcu_[j] ? (Hh - 1 - (HHALF * HKH + fhp_[j]))
                                : (HHALF * HKH + fhp_[j]);   // hofs(fcu, HHALF, fhp)
        foi_[j] = hh0 * 192;
        fstep_[j] = (fcu_[j] ? -HKH : HKH) * 192;
    }
    (void)wsblk192;

    auto hofs = [&](int cur, int P, int hp) -> int {
        const int p = P * HKH + hp;
        return cur ? (Hh - 1 - p) : p;
    };

    float xr_[3], grg = 0.f, orr[2][3];

    // prologue: stage period 0 into buf 0 (incremental offsets)
    {
#pragma unroll
        for (int j = 0; j < 3; ++j) {
            xr_[j] = xb[xoff_[j] + (size_t)xoi_[j]];
            xoi_[j] += xstep_[j];
        }
        if (gst) {
            grg = gp0[goi];
            goi += gstep;
        }
#pragma unroll
        for (int j = 0; j < 3; ++j) xs[0][cu_[j]][hp_[j]][d_[j]][w_[j]] = xr_[j];
        if (gst) gs[0][gcu_][ghp_][gw_][gk_] = grg;
    }
    __syncthreads();

    float A = NEGBIG;

#pragma unroll 2
    for (int p = 0; p < HNP; ++p) {
        const int pb = p & 1;

        // (1) issue staging loads for period p+1 (incremental offsets)
        if (p + 1 < HNP) {
#pragma unroll
            for (int j = 0; j < 3; ++j) {
                xr_[j] = xb[xoff_[j] + (size_t)xoi_[j]];
                xoi_[j] += xstep_[j];
            }
            if (gst) {
                grg = gp0[goi];
                goi += gstep;
            }
        }
        // (2) fallback only: out-reads for THIS period (flushed next period)
        if constexpr (!WS) {
            if (p >= HHALF) {
#pragma unroll
                for (int j = 0; j < 3; ++j)
                    orr[pb][j] = ob[xoff_[j] + (size_t)hofs(cu_[j], p, hp_[j]) * Ww];
            }
        }

        // (3) compute HKH windows
#pragma unroll
        for (int hp = 0; hp < HKH; ++hp) {
            const int q = p * HKH + hp;
            const float cs = xs[pb][dir][hp][dl][col];
            const float* gbase = &gs[pb][dir][hp][col][0];
            const float4 g03 = *reinterpret_cast<const float4*>(gbase);
            const float g4 = gbase[4];
            A = sga_step(A, cs, g03.x, g03.y, g03.z, g03.w, g4, is47, q == 0);
            if (q < Hh / 2) {
                if (lane < Dd) stash[col][dir][q][lane] = (_Float16)A;
            } else {
                const float s = (float)stash[col][dir ^ 1][Hh - 1 - q][dl];
                const float o = fmaxf(A, s);
                if (lane < Dd) osb[pb][dir][hp][lane][col] = o;
            }
        }

        // (4) flush period p-1 osb
        if (p > HHALF) {
            if constexpr (WS) {
#pragma unroll
                for (int j = 0; j < 2; ++j) {
                    if (fval_[j]) {
                        const float* orow = &osb[pb ^ 1][fcu_[j]][fhp_[j]][fd_[j]][0];
                        const unsigned pk =
                            f2h(orow[2 * fu_[j]]) | (f2h(orow[2 * fu_[j] + 1]) << 16);
                        ws[fbase_[j] + (size_t)foi_[j]] = pk;
                        foi_[j] += fstep_[j];
                    }
                }
            } else {
#pragma unroll
                for (int j = 0; j < 3; ++j) {
                    const float v = fmaxf(osb[pb ^ 1][cu_[j]][hp_[j]][d_[j]][w_[j]],
                                          orr[pb ^ 1][j]);
                    ob[xoff_[j] + (size_t)hofs(cu_[j], p - 1, hp_[j]) * Ww] = v;
                }
            }
        }

        // (5) commit staged regs for p+1
        if (p + 1 < HNP) {
#pragma unroll
            for (int j = 0; j < 3; ++j) xs[pb ^ 1][cu_[j]][hp_[j]][d_[j]][w_[j]] = xr_[j];
            if (gst) gs[pb ^ 1][gcu_][ghp_][gw_][gk_] = grg;
        }
        __syncthreads();
    }

    // epilogue: flush last period (p = HNP-1, pb = 1)
    if constexpr (WS) {
#pragma unroll
        for (int j = 0; j < 2; ++j) {
            if (fval_[j]) {
                const float* orow = &osb[1][fcu_[j]][fhp_[j]][fd_[j]][0];
                const unsigned pk = f2h(orow[2 * fu_[j]]) | (f2h(orow[2 * fu_[j] + 1]) << 16);
                ws[fbase_[j] + (size_t)foi_[j]] = pk;
            }
        }
    } else {
#pragma unroll
        for (int j = 0; j < 3; ++j) {
            const float v = fmaxf(osb[1][cu_[j]][hp_[j]][d_[j]][w_[j]], orr[1][j]);
            ob[xoff_[j] + (size_t)hofs(cu_[j], HNP - 1, hp_[j]) * Ww] = v;
        }
    }
}

extern "C" void kernel_launch(void* const* d_in, const int* in_sizes, int n_in,
                              void* d_out, int out_size, void* d_ws, size_t ws_size,
                              hipStream_t stream) {
    const float* x  = (const float*)d_in[0];
    const float* g0 = (const float*)d_in[1];
    const float* g1 = (const float*)d_in[2];
    const float* g2 = (const float*)d_in[3];
    const float* g3 = (const float*)d_in[4];
    float* out = (float*)d_out;

    if (ws_size >= WSNEED) {
        // H pair -> ws (fp16 blocked, no out access); W pair -> out = max(all 4)
        sga_h9<true><<<Cc * (Ww / HWT), 1024, 0, stream>>>(x, g2, g3, out, (unsigned*)d_ws);
        sga_w6<true><<<Cc * Hh, 128, 0, stream>>>(x, g0, g1, out, (const unsigned*)d_ws);
    } else {
        // fallback = round-14 config: W writes out; H RMWs out in fp32.
        sga_w6<false><<<Cc * Hh, 128, 0, stream>>>(x, g0, g1, out, nullptr);
        sga_h9<false><<<Cc * (Ww / HWT), 1024, 0, stream>>>(x, g2, g3, out, nullptr);
    }
}